// Round 1
// 762.604 us; speedup vs baseline: 1.0309x; 1.0309x over previous
//
#include <hip/hip_runtime.h>
#include <cstdint>
#include <cstddef>

#define B_ 64
#define N_ 4096
#define D_ 512
#define A_ 128

typedef unsigned short u16;
typedef __attribute__((ext_vector_type(8))) short bf16x8;   // 8 bf16 in 4 VGPRs
typedef __attribute__((ext_vector_type(4))) float f32x4;

__device__ __forceinline__ u16 cvt_bf16(float x) {
    unsigned u = __float_as_uint(x);
    return (u16)((u + 0x7FFFu + ((u >> 16) & 1u)) >> 16);   // RNE
}
__device__ __forceinline__ unsigned pack2_bf16(float a, float b) {
    unsigned ua = __float_as_uint(a), ub = __float_as_uint(b);
    unsigned ra = (ua + 0x7FFFu + ((ua >> 16) & 1u)) >> 16;
    unsigned rb = (ub + 0x7FFFu + ((ub >> 16) & 1u)) >> 16;
    return ra | (rb << 16);
}
__device__ __forceinline__ float bf2f(unsigned lo16) {
    return __uint_as_float(lo16 << 16);
}
__device__ __forceinline__ float fast_tanh(float x) {
    float ax = fabsf(x);
    float e  = __expf(-2.0f * ax);
    float r  = __fdividef(1.0f - e, 1.0f + e);
    return x < 0.0f ? -r : r;
}

#define WAITVM(N) asm volatile("s_waitcnt vmcnt(" #N ")" ::: "memory")
#define SCHEDB()  __builtin_amdgcn_sched_barrier(0)

// ---------------------------------------------------------------- kernel 0
// blocks 0..63  : W_I [D][A] fp32 -> Wbf fragment-tiled bf16:
//                 frag f = ntile*16 + kslice (ntile=a>>4, kslice=k>>5), each
//                 frag is 1 KB: [quad=(k>>3)&3][l15=a&15][e=k&7] -> a wave's
//                 64 lanes read one frag as a single contiguous 1 KB line.
// blocks 64..127: q_att[b] = tanh(v_Q@W_Q + b_Q); zero sums[b], u_raw[b][:]
__global__ void k_prep(const float* __restrict__ WI, const float* __restrict__ vQ,
                       const float* __restrict__ WQ, const float* __restrict__ bQ,
                       u16* __restrict__ Wbf, float* __restrict__ qatt,
                       float* __restrict__ sums, float* __restrict__ u_raw) {
    const int blk = blockIdx.x, t = threadIdx.x;   // 128 threads
    if (blk < 64) {
        #pragma unroll
        for (int i = 0; i < 2; ++i) {
            int item = blk * 256 + i * 128 + t;    // 16384 items
            int a  = item & 127;
            int d0 = (item >> 7) << 2;             // k base (multiple of 4)
            ushort4 r;
            r.x = cvt_bf16(WI[(d0 + 0) * A_ + a]);
            r.y = cvt_bf16(WI[(d0 + 1) * A_ + a]);
            r.z = cvt_bf16(WI[(d0 + 2) * A_ + a]);
            r.w = cvt_bf16(WI[(d0 + 3) * A_ + a]);
            // fragment-tiled offset (u16 units)
            int off = (a >> 4) * 8192            // ntile
                    + (d0 >> 5) * 512            // kslice
                    + ((d0 >> 3) & 3) * 128      // quad
                    + (a & 15) * 8               // l15
                    + (d0 & 7);                  // elem (0 or 4)
            *(ushort4*)&Wbf[off] = r;
        }
    } else {
        const int b = blk - 64;
        __shared__ float sq[D_];
        for (int d = t; d < D_; d += 128) sq[d] = vQ[b * D_ + d];
        __syncthreads();
        float acc = bQ[t];
        #pragma unroll 8
        for (int d = 0; d < D_; ++d) acc += sq[d] * WQ[d * A_ + t];
        qatt[b * A_ + t] = fast_tanh(acc);
        float4 z = {0.f, 0.f, 0.f, 0.f};
        *(float4*)(u_raw + b * D_ + t * 4) = z;
        if (t == 0) sums[b] = 0.0f;
    }
}

// ---------------------------------------------------------------- kernel 1
// Fused, SINGLE HBM pass over v_I.
// Block = 64 rows of batch b, 512 threads (8 waves: rg=wave>>1 row-group,
// cg=wave&1 col-group). Full 64x512 A tile reg-staged -> bf16 LDS (XOR
// swizzled, T2). B = W_I fragments loaded from L2-hot fragment-tiled global.
// Counted-vmcnt pipeline (T3/T4): raw s_barrier, never vmcnt(0) mid-loop.
// Phase 2 (weighted row-sum) reads the bf16 tile straight from LDS.
__global__ void __launch_bounds__(512, 4)
k_fused(const float* __restrict__ vI, const u16* __restrict__ Wbf,
        const float* __restrict__ qatt, const float* __restrict__ Wp,
        float* __restrict__ wbuf, float* __restrict__ sums,
        float* __restrict__ u_raw) {
    const int b  = blockIdx.y;
    const int n0 = blockIdx.x * 64;
    const int t    = threadIdx.x;
    const int lane = t & 63, wave = t >> 6;
    const int l15  = lane & 15, quad = lane >> 4;
    const int rg = wave >> 1, cg = wave & 1;

    __shared__ u16   sA[64 * 512];     // 64 KB, swizzled bf16 tile, resident all kernel
    __shared__ float sred[2][64];      // cross-wave (cg) logit partials
    __shared__ float sw[64];           // per-row unnormalized softmax weights
    __shared__ float sph[4][512];      // 8 KB phase-2 partials

    // ---- loop-invariant loads FIRST (vm stream positions 1..8) ----
    float qa[4], wp[4];
    #pragma unroll
    for (int nt = 0; nt < 4; ++nt) {
        int a = (cg * 4 + nt) * 16 + l15;
        qa[nt] = qatt[b * A_ + a];
        wp[nt] = Wp[a];
    }
    SCHEDB();

    // ---- A staging addressing: thread -> (row ar, 8 floats at k-off ak) ----
    const int ar = t >> 3;                          // 0..63
    const int ak = (t & 7) * 8;                     // float offset in row
    const float* ag = vI + ((size_t)(b * N_ + n0 + ar) * D_ + ak);
    // LDS write byte addr: row*1024 + (k_byte ^ ((row&7)<<4))  [T2 swizzle]
    char* awb = (char*)sA + ar * 1024 + (((t & 7) * 16) ^ ((ar & 7) << 4));

    const u16* bg = Wbf + lane * 8;                 // lane slot inside a frag

    // A-fragment read base: row = rg*16 + l15
    const int arow = rg * 16 + l15;
    const char* afb = (const char*)sA + arow * 1024;
    const int aswz = (arow & 7) << 4;

    f32x4 acc[4];
    #pragma unroll
    for (int i = 0; i < 4; ++i) acc[i] = (f32x4){0.f, 0.f, 0.f, 0.f};

    float4 areg[2][2];
    // prologue: issue A(0)  (positions 9..10)
    areg[0][0] = *(const float4*)(ag + 0);
    areg[0][1] = *(const float4*)(ag + 4);
    SCHEDB();

    bf16x8 bf0[4], bf1[4];

    // steady-state stream per chunk kr: B(kr,0)[4] B(kr,1)[4] A(kr+1)[2]
    //   A(kr) done  <=> outstanding <= 10   (kr=7: 8)
    //   B(kr,0) done<=> outstanding <= 6    (kr=7: 4)
    //   B(kr,1) done<=> outstanding <= 2    (kr=7: 0)
    // A(kr+1) stays in flight across the whole chunk -> full latency hiding.
    #pragma unroll
    for (int kr = 0; kr < 8; ++kr) {
        #pragma unroll
        for (int nt = 0; nt < 4; ++nt)
            bf0[nt] = *(const bf16x8*)(bg + ((((cg * 4 + nt) * 16) + kr * 2 + 0) << 9));
        SCHEDB();
        #pragma unroll
        for (int nt = 0; nt < 4; ++nt)
            bf1[nt] = *(const bf16x8*)(bg + ((((cg * 4 + nt) * 16) + kr * 2 + 1) << 9));
        SCHEDB();
        if (kr < 7) {
            areg[(kr + 1) & 1][0] = *(const float4*)(ag + (kr + 1) * 64);
            areg[(kr + 1) & 1][1] = *(const float4*)(ag + (kr + 1) * 64 + 4);
        }
        SCHEDB();

        // ---- wait A(kr), convert once, publish to LDS ----
        if (kr < 7) { WAITVM(10); } else { WAITVM(8); }
        {
            float4 x0 = areg[kr & 1][0], x1 = areg[kr & 1][1];
            union { bf16x8 v; unsigned u[4]; } cv;
            cv.u[0] = pack2_bf16(x0.x, x0.y);
            cv.u[1] = pack2_bf16(x0.z, x0.w);
            cv.u[2] = pack2_bf16(x1.x, x1.y);
            cv.u[3] = pack2_bf16(x1.z, x1.w);
            *(bf16x8*)(awb + kr * 128) = cv.v;
        }
        SCHEDB();
        asm volatile("s_waitcnt lgkmcnt(0)" ::: "memory");
        __builtin_amdgcn_s_barrier();
        SCHEDB();

        // ---- ks = 0 ----
        if (kr < 7) { WAITVM(6); } else { WAITVM(4); }
        {
            bf16x8 af = *(const bf16x8*)(afb + kr * 128 + ((quad * 16) ^ aswz));
            #pragma unroll
            for (int nt = 0; nt < 4; ++nt)
                acc[nt] = __builtin_amdgcn_mfma_f32_16x16x32_bf16(af, bf0[nt], acc[nt], 0, 0, 0);
        }
        SCHEDB();
        // ---- ks = 1 ----
        if (kr < 7) { WAITVM(2); } else { WAITVM(0); }
        {
            bf16x8 af = *(const bf16x8*)(afb + kr * 128 + ((64 + quad * 16) ^ aswz));
            #pragma unroll
            for (int nt = 0; nt < 4; ++nt)
                acc[nt] = __builtin_amdgcn_mfma_f32_16x16x32_bf16(af, bf1[nt], acc[nt], 0, 0, 0);
        }
        SCHEDB();
    }

    // ---- epilogue: logits -> w = exp(logit); C row = quad*4+r, col = l15 ----
    #pragma unroll
    for (int r = 0; r < 4; ++r) {
        float s = 0.f;
        #pragma unroll
        for (int nt = 0; nt < 4; ++nt) {
            float t1 = fast_tanh(acc[nt][r]);
            float h  = fast_tanh(t1 + qa[nt]);
            s += h * wp[nt];
        }
        s += __shfl_xor(s, 1, 16);
        s += __shfl_xor(s, 2, 16);
        s += __shfl_xor(s, 4, 16);
        s += __shfl_xor(s, 8, 16);
        if (l15 == 0) sred[cg][rg * 16 + quad * 4 + r] = s;
    }
    __syncthreads();
    if (t < 64) {
        // |logit| <= sum|W_p| ~ 9 -> exp safe in fp32; no max-sub needed
        float we = __expf(sred[0][t] + sred[1][t]);
        sw[t] = we;
        wbuf[(size_t)b * N_ + n0 + t] = we;
        float ls = we;
        ls += __shfl_xor(ls, 1);
        ls += __shfl_xor(ls, 2);
        ls += __shfl_xor(ls, 4);
        ls += __shfl_xor(ls, 8);
        ls += __shfl_xor(ls, 16);
        ls += __shfl_xor(ls, 32);
        if (t == 0) atomicAdd(sums + b, ls);
    }
    __syncthreads();

    // ---- phase 2: weighted row-sum straight from LDS (zero extra HBM) ----
    const int dg = t & 127;            // float4 column group 0..127
    const int rr = t >> 7;             // 0..3 row-phase
    float p0 = 0.f, p1 = 0.f, p2 = 0.f, p3 = 0.f;
    #pragma unroll
    for (int i = 0; i < 16; ++i) {
        int n = i * 4 + rr;
        const char* src = (const char*)sA + n * 1024 + ((dg * 8) ^ ((n & 7) << 4));
        uint2 wv = *(const uint2*)src;
        float wn = sw[n];
        p0 += wn * bf2f(wv.x & 0xffffu);
        p1 += wn * bf2f(wv.x >> 16);
        p2 += wn * bf2f(wv.y & 0xffffu);
        p3 += wn * bf2f(wv.y >> 16);
    }
    *(float4*)&sph[rr][dg * 4] = (float4){p0, p1, p2, p3};
    __syncthreads();
    {
        int d = t;                     // 512 threads = 512 columns
        float v = sph[0][d] + sph[1][d] + sph[2][d] + sph[3][d];
        atomicAdd(u_raw + (size_t)b * D_ + d, v);
    }
}

// ---------------------------------------------------------------- kernel 2
// p[b][n] = w[b][n]/S_b ;  u[b][d] = u_raw[b][d]/S_b + v_Q[b][d]
__global__ void __launch_bounds__(256)
k_fin(const float* __restrict__ wbuf, const float* __restrict__ sums,
      const float* __restrict__ u_raw, const float* __restrict__ vQ,
      float* __restrict__ p_out, float* __restrict__ u_out) {
    const int b = blockIdx.x, t = threadIdx.x;    // 256 threads
    const float inv = 1.0f / sums[b];
    #pragma unroll
    for (int i = 0; i < 4; ++i) {
        float4 x = *(const float4*)(wbuf + (size_t)b * N_ + i * 1024 + t * 4);
        float4 y = { x.x * inv, x.y * inv, x.z * inv, x.w * inv };
        *(float4*)(p_out + (size_t)b * N_ + i * 1024 + t * 4) = y;
    }
    if (t < 128) {
        float4 ur = *(const float4*)(u_raw + b * D_ + t * 4);
        float4 vq = *(const float4*)(vQ + b * D_ + t * 4);
        float4 o  = { ur.x * inv + vq.x, ur.y * inv + vq.y,
                      ur.z * inv + vq.z, ur.w * inv + vq.w };
        *(float4*)(u_out + b * D_ + t * 4) = o;
    }
}

// ----------------------------------------------------------------
extern "C" void kernel_launch(void* const* d_in, const int* in_sizes, int n_in,
                              void* d_out, int out_size, void* d_ws, size_t ws_size,
                              hipStream_t stream) {
    const float* vI = (const float*)d_in[0];
    const float* vQ = (const float*)d_in[1];
    const float* WI = (const float*)d_in[2];
    const float* WQ = (const float*)d_in[3];
    const float* bQ = (const float*)d_in[4];
    const float* Wp = (const float*)d_in[5];
    // d_in[6] (b_p): constant added to all logits -> cancels in softmax.

    float* out_p = (float*)d_out;                    // [B][N]
    float* out_u = out_p + (size_t)B_ * N_;          // [B][D]

    char* ws = (char*)d_ws;
    u16*   Wbf   = (u16*)ws;                             // 128 KiB @ 0
    float* qatt  = (float*)(ws + 131072);                // 32 KiB
    float* sums  = (float*)(ws + 163840);                // 1 KiB
    float* u_raw = (float*)(ws + 164864);                // 128 KiB
    float* wbuf  = (float*)(ws + 295936);                // 1 MiB

    k_prep<<<128, 128, 0, stream>>>(WI, vQ, WQ, bQ, Wbf, qatt, sums, u_raw);
    k_fused<<<dim3(N_ / 64, B_), 512, 0, stream>>>(vI, Wbf, qatt, Wp,
                                                   wbuf, sums, u_raw);
    k_fin<<<B_, 256, 0, stream>>>(wbuf, sums, u_raw, vQ, out_p, out_u);
}

// Round 2
// 748.828 us; speedup vs baseline: 1.0498x; 1.0184x over previous
//
#include <hip/hip_runtime.h>
#include <cstdint>
#include <cstddef>

#define B_ 64
#define N_ 4096
#define D_ 512
#define A_ 128

typedef unsigned short u16;
typedef __attribute__((ext_vector_type(8))) short bf16x8;   // 8 bf16 in 4 VGPRs
typedef __attribute__((ext_vector_type(4))) float f32x4;

__device__ __forceinline__ u16 cvt_bf16(float x) {
    unsigned u = __float_as_uint(x);
    return (u16)((u + 0x7FFFu + ((u >> 16) & 1u)) >> 16);   // RNE
}
__device__ __forceinline__ unsigned pack2_bf16(float a, float b) {
    unsigned ua = __float_as_uint(a), ub = __float_as_uint(b);
    unsigned ra = (ua + 0x7FFFu + ((ua >> 16) & 1u)) >> 16;
    unsigned rb = (ub + 0x7FFFu + ((ub >> 16) & 1u)) >> 16;
    return ra | (rb << 16);
}
__device__ __forceinline__ float bf2f(unsigned lo16) {
    return __uint_as_float(lo16 << 16);
}
__device__ __forceinline__ float fast_tanh(float x) {
    float ax = fabsf(x);
    float e  = __expf(-2.0f * ax);
    float r  = __fdividef(1.0f - e, 1.0f + e);
    return x < 0.0f ? -r : r;
}
// async global->LDS, 16 B per lane, LDS dest = wave-uniform base + lane*16
__device__ __forceinline__ void gl_lds16(const void* g, void* l) {
    __builtin_amdgcn_global_load_lds(
        (const __attribute__((address_space(1))) unsigned int*)g,
        (__attribute__((address_space(3))) unsigned int*)l, 16, 0, 0);
}

#define WAITVM(N) asm volatile("s_waitcnt vmcnt(" #N ")" ::: "memory")
#define SCHEDB()  __builtin_amdgcn_sched_barrier(0)

// ---------------------------------------------------------------- kernel 0
// blocks 0..63  : W_I [D][A] fp32 -> Wbf fragment-tiled bf16:
//                 frag f = ntile*16 + kslice, each frag 1 KB laid out so a
//                 wave's 64 lanes read it as one contiguous 1 KB line
//                 (lane l holds W[a=ntile*16+(l&15)][k=kslice*32+(l>>4)*8 ..+8]).
// blocks 64..127: q_att[b] = tanh(v_Q@W_Q + b_Q); zero sums[b], u_raw[b][:]
__global__ void k_prep(const float* __restrict__ WI, const float* __restrict__ vQ,
                       const float* __restrict__ WQ, const float* __restrict__ bQ,
                       u16* __restrict__ Wbf, float* __restrict__ qatt,
                       float* __restrict__ sums, float* __restrict__ u_raw) {
    const int blk = blockIdx.x, t = threadIdx.x;   // 128 threads
    if (blk < 64) {
        #pragma unroll
        for (int i = 0; i < 2; ++i) {
            int item = blk * 256 + i * 128 + t;    // 16384 items
            int a  = item & 127;
            int d0 = (item >> 7) << 2;             // k base (multiple of 4)
            ushort4 r;
            r.x = cvt_bf16(WI[(d0 + 0) * A_ + a]);
            r.y = cvt_bf16(WI[(d0 + 1) * A_ + a]);
            r.z = cvt_bf16(WI[(d0 + 2) * A_ + a]);
            r.w = cvt_bf16(WI[(d0 + 3) * A_ + a]);
            // fragment-tiled offset (u16 units)
            int off = (a >> 4) * 8192            // ntile
                    + (d0 >> 5) * 512            // kslice
                    + ((d0 >> 3) & 3) * 128      // quad
                    + (a & 15) * 8               // l15
                    + (d0 & 7);                  // elem (0 or 4)
            *(ushort4*)&Wbf[off] = r;
        }
    } else {
        const int b = blk - 64;
        __shared__ float sq[D_];
        for (int d = t; d < D_; d += 128) sq[d] = vQ[b * D_ + d];
        __syncthreads();
        float acc = bQ[t];
        #pragma unroll 8
        for (int d = 0; d < D_; ++d) acc += sq[d] * WQ[d * A_ + t];
        qatt[b * A_ + t] = fast_tanh(acc);
        float4 z = {0.f, 0.f, 0.f, 0.f};
        *(float4*)(u_raw + b * D_ + t * 4) = z;
        if (t == 0) sums[b] = 0.0f;
    }
}

// ---------------------------------------------------------------- kernel 1
// Fused, single HBM pass over v_I. Block = 64 rows, 512 threads (8 waves:
// rg=wave>>1 row-group, cg=wave&1 col-group).
// Per chunk kr (K=64 slice):
//   issue gl_lds B(kr) (16 KB block-wide, each wave DMAs its own ntile) |
//   issue A(kr+1) reg loads | WAITVM(A(kr)) -> convert -> ds_write sA |
//   WAITVM(B dma done, A(kr+1) stays in flight) | lgkm0+barrier |
//   MFMA (setprio 1) | barrier (protects sB for next DMA).
// B L2 traffic: 16 KB/chunk/block (was 64 KB: 4 waves duplicated loads).
// Phase 2 reads the retained bf16 sA tile (zero extra HBM).
__global__ void __launch_bounds__(512, 4)
k_fused(const float* __restrict__ vI, const u16* __restrict__ Wbf,
        const float* __restrict__ qatt, const float* __restrict__ Wp,
        float* __restrict__ wbuf, float* __restrict__ sums,
        float* __restrict__ u_raw) {
    const int b  = blockIdx.y;
    const int n0 = blockIdx.x * 64;
    const int t    = threadIdx.x;
    const int lane = t & 63, wave = t >> 6;
    const int l15  = lane & 15, quad = lane >> 4;
    const int rg = wave >> 1, cg = wave & 1;

    __shared__ __align__(16) char smem[81920];   // exactly 80 KB -> 2 blocks/CU
    u16*  sA = (u16*)smem;                        // 64 KB retained bf16 tile
    char* sB = smem + 65536;                      // 16 KB B chunk staging
    // epilogue overlays of the dead sB region:
    float* sph  = (float*)sB;                     // [4][512]  8 KB
    float* sw   = (float*)(sB + 8192);            // [64]
    float* sred = (float*)(sB + 8448);            // [2][64]

    // ---- loop-invariant loads (8 vmem, drained in prologue) ----
    float qa[4], wp[4];
    #pragma unroll
    for (int nt = 0; nt < 4; ++nt) {
        int a = (cg * 4 + nt) * 16 + l15;
        qa[nt] = qatt[b * A_ + a];
        wp[nt] = Wp[a];
    }
    SCHEDB();

    // ---- A staging: thread t -> (row ar, 8 floats at akx*8 + kr*64) ----
    const int ar  = t >> 3;
    const int akx = t & 7;
    const float* ag = vI + ((size_t)(b * N_ + n0 + ar) * D_ + akx * 8);
    char* awb = (char*)sA + ar * 1024 + ((akx * 16) ^ ((ar & 7) << 4));  // T2 swz

    // ---- B staging: wave w DMAs ntile w, kslices kr*2, kr*2+1 ----
    const u16* bsrc = Wbf + (size_t)(wave * 16) * 512 + lane * 8;  // +(kr*2+ks)*512
    char* bdst = sB + wave * 2048;                                 // + ks*1024

    // ---- fragment read bases ----
    const int arow = rg * 16 + l15;
    const char* afb = (const char*)sA + arow * 1024;
    const int aswz = (arow & 7) << 4;
    const char* bfb = sB + (cg * 4) * 2048 + lane * 16;            // +nt*2048+ks*1024

    f32x4 acc[4];
    #pragma unroll
    for (int i = 0; i < 4; ++i) acc[i] = (f32x4){0.f, 0.f, 0.f, 0.f};

    float4 areg[2][2];
    areg[0][0] = *(const float4*)(ag + 0);
    areg[0][1] = *(const float4*)(ag + 4);
    WAITVM(2);          // drain qa/wp; A(0) stays in flight
    SCHEDB();

    // vm queue invariant at chunk entry: [A(kr): 2]
    #pragma unroll
    for (int kr = 0; kr < 8; ++kr) {
        // 1. B(kr) DMA -> LDS                       queue: [A2, B2]
        gl_lds16(bsrc + (kr * 2 + 0) * 512, bdst);
        gl_lds16(bsrc + (kr * 2 + 1) * 512, bdst + 1024);
        SCHEDB();
        // 2. A(kr+1) prefetch                       queue: [A2, B2, A'2]
        if (kr < 7) {
            areg[(kr + 1) & 1][0] = *(const float4*)(ag + (kr + 1) * 64);
            areg[(kr + 1) & 1][1] = *(const float4*)(ag + (kr + 1) * 64 + 4);
        }
        SCHEDB();
        // 3. wait A(kr); convert once; publish to sA
        if (kr < 7) { WAITVM(4); } else { WAITVM(2); }
        {
            float4 x0 = areg[kr & 1][0], x1 = areg[kr & 1][1];
            union { bf16x8 v; unsigned u[4]; } cv;
            cv.u[0] = pack2_bf16(x0.x, x0.y);
            cv.u[1] = pack2_bf16(x0.z, x0.w);
            cv.u[2] = pack2_bf16(x1.x, x1.y);
            cv.u[3] = pack2_bf16(x1.z, x1.w);
            *(bf16x8*)(awb + kr * 128) = cv.v;
        }
        SCHEDB();
        // 4. wait B DMA landed (A(kr+1) stays in flight)
        if (kr < 7) { WAITVM(2); } else { WAITVM(0); }
        asm volatile("s_waitcnt lgkmcnt(0)" ::: "memory");
        __builtin_amdgcn_s_barrier();            // sA(kr)+sB(kr) ready, all waves
        SCHEDB();
        // 5. MFMA cluster
        __builtin_amdgcn_s_setprio(1);
        #pragma unroll
        for (int ks = 0; ks < 2; ++ks) {
            bf16x8 af = *(const bf16x8*)(afb + kr * 128 + ((ks * 64 + quad * 16) ^ aswz));
            #pragma unroll
            for (int nt = 0; nt < 4; ++nt) {
                bf16x8 bv = *(const bf16x8*)(bfb + nt * 2048 + ks * 1024);
                acc[nt] = __builtin_amdgcn_mfma_f32_16x16x32_bf16(af, bv, acc[nt], 0, 0, 0);
            }
        }
        __builtin_amdgcn_s_setprio(0);
        SCHEDB();
        // 6. all waves done reading sB(kr) before next chunk's DMA
        __builtin_amdgcn_s_barrier();
        SCHEDB();
    }

    // ---- epilogue: logits -> w = exp(logit); C row = quad*4+r, col = l15 ----
    #pragma unroll
    for (int r = 0; r < 4; ++r) {
        float s = 0.f;
        #pragma unroll
        for (int nt = 0; nt < 4; ++nt) {
            float t1 = fast_tanh(acc[nt][r]);
            float h  = fast_tanh(t1 + qa[nt]);
            s += h * wp[nt];
        }
        s += __shfl_xor(s, 1, 16);
        s += __shfl_xor(s, 2, 16);
        s += __shfl_xor(s, 4, 16);
        s += __shfl_xor(s, 8, 16);
        if (l15 == 0) sred[cg * 64 + rg * 16 + quad * 4 + r] = s;
    }
    __syncthreads();
    if (t < 64) {
        // |logit| <= sum|W_p| ~ 9 -> exp safe in fp32; no max-sub needed
        float we = __expf(sred[t] + sred[64 + t]);
        sw[t] = we;
        wbuf[(size_t)b * N_ + n0 + t] = we;
        float ls = we;
        ls += __shfl_xor(ls, 1);
        ls += __shfl_xor(ls, 2);
        ls += __shfl_xor(ls, 4);
        ls += __shfl_xor(ls, 8);
        ls += __shfl_xor(ls, 16);
        ls += __shfl_xor(ls, 32);
        if (t == 0) atomicAdd(sums + b, ls);
    }
    __syncthreads();

    // ---- phase 2: weighted row-sum straight from retained LDS tile ----
    const int dg = t & 127;            // float4 column group 0..127
    const int rr = t >> 7;             // 0..3 row-phase
    float p0 = 0.f, p1 = 0.f, p2 = 0.f, p3 = 0.f;
    #pragma unroll
    for (int i = 0; i < 16; ++i) {
        int n = i * 4 + rr;
        const char* src = (const char*)sA + n * 1024 + ((dg * 8) ^ ((n & 7) << 4));
        uint2 wv = *(const uint2*)src;
        float wn = sw[n];
        p0 += wn * bf2f(wv.x & 0xffffu);
        p1 += wn * bf2f(wv.x >> 16);
        p2 += wn * bf2f(wv.y & 0xffffu);
        p3 += wn * bf2f(wv.y >> 16);
    }
    *(float4*)(sph + rr * 512 + dg * 4) = (float4){p0, p1, p2, p3};
    __syncthreads();
    {
        int d = t;                     // 512 threads = 512 columns
        float v = sph[d] + sph[512 + d] + sph[1024 + d] + sph[1536 + d];
        atomicAdd(u_raw + (size_t)b * D_ + d, v);
    }
}

// ---------------------------------------------------------------- kernel 2
// p[b][n] = w[b][n]/S_b ;  u[b][d] = u_raw[b][d]/S_b + v_Q[b][d]
// 256 blocks (b x quarter) for latency hiding.
__global__ void __launch_bounds__(256)
k_fin(const float* __restrict__ wbuf, const float* __restrict__ sums,
      const float* __restrict__ u_raw, const float* __restrict__ vQ,
      float* __restrict__ p_out, float* __restrict__ u_out) {
    const int b = blockIdx.x, q = blockIdx.y, t = threadIdx.x;   // 256 threads
    const float inv = 1.0f / sums[b];
    {
        size_t off = (size_t)b * N_ + q * 1024 + t * 4;
        float4 x = *(const float4*)(wbuf + off);
        float4 y = { x.x * inv, x.y * inv, x.z * inv, x.w * inv };
        *(float4*)(p_out + off) = y;
    }
    if (q == 0 && t < 128) {
        float4 ur = *(const float4*)(u_raw + b * D_ + t * 4);
        float4 vq = *(const float4*)(vQ + b * D_ + t * 4);
        float4 o  = { ur.x * inv + vq.x, ur.y * inv + vq.y,
                      ur.z * inv + vq.z, ur.w * inv + vq.w };
        *(float4*)(u_out + b * D_ + t * 4) = o;
    }
}

// ----------------------------------------------------------------
extern "C" void kernel_launch(void* const* d_in, const int* in_sizes, int n_in,
                              void* d_out, int out_size, void* d_ws, size_t ws_size,
                              hipStream_t stream) {
    const float* vI = (const float*)d_in[0];
    const float* vQ = (const float*)d_in[1];
    const float* WI = (const float*)d_in[2];
    const float* WQ = (const float*)d_in[3];
    const float* bQ = (const float*)d_in[4];
    const float* Wp = (const float*)d_in[5];
    // d_in[6] (b_p): constant added to all logits -> cancels in softmax.

    float* out_p = (float*)d_out;                    // [B][N]
    float* out_u = out_p + (size_t)B_ * N_;          // [B][D]

    char* ws = (char*)d_ws;
    u16*   Wbf   = (u16*)ws;                             // 128 KiB @ 0
    float* qatt  = (float*)(ws + 131072);                // 32 KiB
    float* sums  = (float*)(ws + 163840);                // 1 KiB
    float* u_raw = (float*)(ws + 164864);                // 128 KiB
    float* wbuf  = (float*)(ws + 295936);                // 1 MiB

    k_prep<<<128, 128, 0, stream>>>(WI, vQ, WQ, bQ, Wbf, qatt, sums, u_raw);
    k_fused<<<dim3(N_ / 64, B_), 512, 0, stream>>>(vI, Wbf, qatt, Wp,
                                                   wbuf, sums, u_raw);
    k_fin<<<dim3(B_, 4), 256, 0, stream>>>(wbuf, sums, u_raw, vQ, out_p, out_u);
}

// Round 3
// 748.018 us; speedup vs baseline: 1.0510x; 1.0011x over previous
//
#include <hip/hip_runtime.h>
#include <cstdint>
#include <cstddef>

#define B_ 64
#define N_ 4096
#define D_ 512
#define A_ 128

typedef unsigned short u16;
typedef __attribute__((ext_vector_type(8))) short bf16x8;   // 8 bf16 in 4 VGPRs
typedef __attribute__((ext_vector_type(4))) float f32x4;

__device__ __forceinline__ u16 cvt_bf16(float x) {
    unsigned u = __float_as_uint(x);
    return (u16)((u + 0x7FFFu + ((u >> 16) & 1u)) >> 16);   // RNE
}
__device__ __forceinline__ unsigned pack2_bf16(float a, float b) {
    unsigned ua = __float_as_uint(a), ub = __float_as_uint(b);
    unsigned ra = (ua + 0x7FFFu + ((ua >> 16) & 1u)) >> 16;
    unsigned rb = (ub + 0x7FFFu + ((ub >> 16) & 1u)) >> 16;
    return ra | (rb << 16);
}
__device__ __forceinline__ float bf2f(unsigned lo16) {
    return __uint_as_float(lo16 << 16);
}
__device__ __forceinline__ float fast_tanh(float x) {
    float ax = fabsf(x);
    float e  = __expf(-2.0f * ax);
    float r  = __fdividef(1.0f - e, 1.0f + e);
    return x < 0.0f ? -r : r;
}

#define WAITVM(N) asm volatile("s_waitcnt vmcnt(" #N ")" ::: "memory")
#define SCHEDB()  __builtin_amdgcn_sched_barrier(0)

// ---------------------------------------------------------------- kernel 0
// blocks 0..63  : W_I [D][A] fp32 -> Wbf fragment-tiled bf16:
//                 frag f = ntile*16 + kslice, each frag 1 KB laid out so a
//                 wave's 64 lanes read it as one contiguous 1 KB line
//                 (lane l holds W[a=ntile*16+(l&15)][k=kslice*32+(l>>4)*8 ..+8]).
// blocks 64..127: q_att[b] = tanh(v_Q@W_Q + b_Q); zero sums[b], u_raw[b][:]
__global__ void k_prep(const float* __restrict__ WI, const float* __restrict__ vQ,
                       const float* __restrict__ WQ, const float* __restrict__ bQ,
                       u16* __restrict__ Wbf, float* __restrict__ qatt,
                       float* __restrict__ sums, float* __restrict__ u_raw) {
    const int blk = blockIdx.x, t = threadIdx.x;   // 128 threads
    if (blk < 64) {
        #pragma unroll
        for (int i = 0; i < 2; ++i) {
            int item = blk * 256 + i * 128 + t;    // 16384 items
            int a  = item & 127;
            int d0 = (item >> 7) << 2;             // k base (multiple of 4)
            ushort4 r;
            r.x = cvt_bf16(WI[(d0 + 0) * A_ + a]);
            r.y = cvt_bf16(WI[(d0 + 1) * A_ + a]);
            r.z = cvt_bf16(WI[(d0 + 2) * A_ + a]);
            r.w = cvt_bf16(WI[(d0 + 3) * A_ + a]);
            // fragment-tiled offset (u16 units)
            int off = (a >> 4) * 8192            // ntile
                    + (d0 >> 5) * 512            // kslice
                    + ((d0 >> 3) & 3) * 128      // quad
                    + (a & 15) * 8               // l15
                    + (d0 & 7);                  // elem (0 or 4)
            *(ushort4*)&Wbf[off] = r;
        }
    } else {
        const int b = blk - 64;
        __shared__ float sq[D_];
        for (int d = t; d < D_; d += 128) sq[d] = vQ[b * D_ + d];
        __syncthreads();
        float acc = bQ[t];
        #pragma unroll 8
        for (int d = 0; d < D_; ++d) acc += sq[d] * WQ[d * A_ + t];
        qatt[b * A_ + t] = fast_tanh(acc);
        float4 z = {0.f, 0.f, 0.f, 0.f};
        *(float4*)(u_raw + b * D_ + t * 4) = z;
        if (t == 0) sums[b] = 0.0f;
    }
}

// ---------------------------------------------------------------- kernel 1
// Fused, single HBM pass over v_I. Block = 64 rows, 512 threads (8 waves:
// rg=wave>>1 row-group, cg=wave&1 col-group).
// B (W-fragments, L1/L2-hot) lives in REGISTERS, double-buffered one chunk
// ahead -> no B-LDS, no B-wait exposure, ONE barrier per chunk (sA RAW only;
// each sA column is written exactly once -> no WAR hazard).
// vm queue per chunk kr (strictly counted, never vmcnt(0) until kr=7):
//   entry [A(kr)2, B(kr)8] -> WAITVM(8) A ready -> issue A(kr+1) ->
//   convert+ds_write sA -> issue B(kr+1) -> WAITVM(10) B ready ->
//   lgkm0 + s_barrier -> MFMA (setprio).
// Phase 2 reads the retained bf16 sA tile (zero extra HBM).
__global__ void __launch_bounds__(512, 4)
k_fused(const float* __restrict__ vI, const u16* __restrict__ Wbf,
        const float* __restrict__ qatt, const float* __restrict__ Wp,
        float* __restrict__ wbuf, float* __restrict__ sums,
        float* __restrict__ u_raw) {
    const int b  = blockIdx.y;
    const int n0 = blockIdx.x * 64;
    const int t    = threadIdx.x;
    const int lane = t & 63, wave = t >> 6;
    const int l15  = lane & 15, quad = lane >> 4;
    const int rg = wave >> 1, cg = wave & 1;

    __shared__ __align__(16) char smem[74496];    // 72.75 KB -> 2 blocks/CU
    u16*   sA   = (u16*)smem;                     // 64 KB retained bf16 tile
    float* sph  = (float*)(smem + 65536);         // [4][512]  8 KB
    float* sw   = (float*)(smem + 73728);         // [64]
    float* sred = (float*)(smem + 73984);         // [2][64]

    // ---- A staging: thread t -> (row ar, 8 floats at akx*8 + kr*64) ----
    const int ar  = t >> 3;
    const int akx = t & 7;
    const float* ag = vI + ((size_t)(b * N_ + n0 + ar) * D_ + akx * 8);
    char* awb = (char*)sA + ar * 1024 + ((akx * 16) ^ ((ar & 7) << 4));  // T2 swz

    // ---- B fragment addressing (global, fragment-tiled) ----
    const u16* bg = Wbf + lane * 8;               // + frag*512 (u16 units)

    // ---- A fragment read base ----
    const int arow = rg * 16 + l15;
    const char* afb = (const char*)sA + arow * 1024;
    const int aswz = (arow & 7) << 4;

    f32x4 acc[4];
    #pragma unroll
    for (int i = 0; i < 4; ++i) acc[i] = (f32x4){0.f, 0.f, 0.f, 0.f};

    float4  areg[2][2];
    bf16x8  breg[2][8];

    // ---- prologue: A(0) then B(0) -> entry invariant [A2, B8] ----
    areg[0][0] = *(const float4*)(ag + 0);
    areg[0][1] = *(const float4*)(ag + 4);
    SCHEDB();
    #pragma unroll
    for (int nt = 0; nt < 4; ++nt) {
        breg[0][nt * 2 + 0] = *(const bf16x8*)(bg + ((((cg * 4 + nt) * 16) + 0) << 9));
        breg[0][nt * 2 + 1] = *(const bf16x8*)(bg + ((((cg * 4 + nt) * 16) + 1) << 9));
    }
    SCHEDB();

    #pragma unroll
    for (int kr = 0; kr < 8; ++kr) {
        const int cur = kr & 1, nxt = cur ^ 1;
        // 1. A(kr) regs ready (outstanding <= B(kr)8)
        WAITVM(8);
        SCHEDB();
        // 2. prefetch A(kr+1)
        if (kr < 7) {
            areg[nxt][0] = *(const float4*)(ag + (kr + 1) * 64);
            areg[nxt][1] = *(const float4*)(ag + (kr + 1) * 64 + 4);
        }
        SCHEDB();
        // 3. convert A(kr) once; publish to sA
        {
            float4 x0 = areg[cur][0], x1 = areg[cur][1];
            union { bf16x8 v; unsigned u[4]; } cv;
            cv.u[0] = pack2_bf16(x0.x, x0.y);
            cv.u[1] = pack2_bf16(x0.z, x0.w);
            cv.u[2] = pack2_bf16(x1.x, x1.y);
            cv.u[3] = pack2_bf16(x1.z, x1.w);
            *(bf16x8*)(awb + kr * 128) = cv.v;
        }
        SCHEDB();
        // 4. prefetch B(kr+1)
        if (kr < 7) {
            #pragma unroll
            for (int nt = 0; nt < 4; ++nt) {
                breg[nxt][nt * 2 + 0] = *(const bf16x8*)(bg + ((((cg * 4 + nt) * 16) + (kr + 1) * 2 + 0) << 9));
                breg[nxt][nt * 2 + 1] = *(const bf16x8*)(bg + ((((cg * 4 + nt) * 16) + (kr + 1) * 2 + 1) << 9));
            }
        }
        SCHEDB();
        // 5. B(kr) regs ready (A'/B' stay in flight); sA(kr) visible to all
        if (kr < 7) { WAITVM(10); } else { WAITVM(0); }
        asm volatile("s_waitcnt lgkmcnt(0)" ::: "memory");
        SCHEDB();
        __builtin_amdgcn_s_barrier();
        SCHEDB();
        // 6. MFMA cluster
        __builtin_amdgcn_s_setprio(1);
        #pragma unroll
        for (int ks = 0; ks < 2; ++ks) {
            bf16x8 af = *(const bf16x8*)(afb + kr * 128 + ((ks * 64 + quad * 16) ^ aswz));
            #pragma unroll
            for (int nt = 0; nt < 4; ++nt)
                acc[nt] = __builtin_amdgcn_mfma_f32_16x16x32_bf16(af, breg[cur][nt * 2 + ks], acc[nt], 0, 0, 0);
        }
        __builtin_amdgcn_s_setprio(0);
        SCHEDB();
    }

    // ---- epilogue: logits -> w = exp(logit); C row = quad*4+r, col = l15 ----
    float qa[4], wp[4];
    #pragma unroll
    for (int nt = 0; nt < 4; ++nt) {
        int a = (cg * 4 + nt) * 16 + l15;
        qa[nt] = qatt[b * A_ + a];
        wp[nt] = Wp[a];
    }
    #pragma unroll
    for (int r = 0; r < 4; ++r) {
        float s = 0.f;
        #pragma unroll
        for (int nt = 0; nt < 4; ++nt) {
            float t1 = fast_tanh(acc[nt][r]);
            float h  = fast_tanh(t1 + qa[nt]);
            s += h * wp[nt];
        }
        s += __shfl_xor(s, 1, 16);
        s += __shfl_xor(s, 2, 16);
        s += __shfl_xor(s, 4, 16);
        s += __shfl_xor(s, 8, 16);
        if (l15 == 0) sred[cg * 64 + rg * 16 + quad * 4 + r] = s;
    }
    __syncthreads();
    if (t < 64) {
        // |logit| <= sum|W_p| ~ 9 -> exp safe in fp32; no max-sub needed
        float we = __expf(sred[t] + sred[64 + t]);
        sw[t] = we;
        wbuf[(size_t)b * N_ + n0 + t] = we;
        float ls = we;
        ls += __shfl_xor(ls, 1);
        ls += __shfl_xor(ls, 2);
        ls += __shfl_xor(ls, 4);
        ls += __shfl_xor(ls, 8);
        ls += __shfl_xor(ls, 16);
        ls += __shfl_xor(ls, 32);
        if (t == 0) atomicAdd(sums + b, ls);
    }
    __syncthreads();

    // ---- phase 2: weighted row-sum straight from retained LDS tile ----
    const int dg = t & 127;            // float4 column group 0..127
    const int rr = t >> 7;             // 0..3 row-phase
    float p0 = 0.f, p1 = 0.f, p2 = 0.f, p3 = 0.f;
    #pragma unroll
    for (int i = 0; i < 16; ++i) {
        int n = i * 4 + rr;
        const char* src = (const char*)sA + n * 1024 + ((dg * 8) ^ ((n & 7) << 4));
        uint2 wv = *(const uint2*)src;
        float wn = sw[n];
        p0 += wn * bf2f(wv.x & 0xffffu);
        p1 += wn * bf2f(wv.x >> 16);
        p2 += wn * bf2f(wv.y & 0xffffu);
        p3 += wn * bf2f(wv.y >> 16);
    }
    *(float4*)(sph + rr * 512 + dg * 4) = (float4){p0, p1, p2, p3};
    __syncthreads();
    {
        int d = t;                     // 512 threads = 512 columns
        float v = sph[d] + sph[512 + d] + sph[1024 + d] + sph[1536 + d];
        atomicAdd(u_raw + (size_t)b * D_ + d, v);
    }
}

// ---------------------------------------------------------------- kernel 2
// p[b][n] = w[b][n]/S_b ;  u[b][d] = u_raw[b][d]/S_b + v_Q[b][d]
// 256 blocks (b x quarter) for latency hiding.
__global__ void __launch_bounds__(256)
k_fin(const float* __restrict__ wbuf, const float* __restrict__ sums,
      const float* __restrict__ u_raw, const float* __restrict__ vQ,
      float* __restrict__ p_out, float* __restrict__ u_out) {
    const int b = blockIdx.x, q = blockIdx.y, t = threadIdx.x;   // 256 threads
    const float inv = 1.0f / sums[b];
    {
        size_t off = (size_t)b * N_ + q * 1024 + t * 4;
        float4 x = *(const float4*)(wbuf + off);
        float4 y = { x.x * inv, x.y * inv, x.z * inv, x.w * inv };
        *(float4*)(p_out + off) = y;
    }
    if (q == 0 && t < 128) {
        float4 ur = *(const float4*)(u_raw + b * D_ + t * 4);
        float4 vq = *(const float4*)(vQ + b * D_ + t * 4);
        float4 o  = { ur.x * inv + vq.x, ur.y * inv + vq.y,
                      ur.z * inv + vq.z, ur.w * inv + vq.w };
        *(float4*)(u_out + b * D_ + t * 4) = o;
    }
}

// ----------------------------------------------------------------
extern "C" void kernel_launch(void* const* d_in, const int* in_sizes, int n_in,
                              void* d_out, int out_size, void* d_ws, size_t ws_size,
                              hipStream_t stream) {
    const float* vI = (const float*)d_in[0];
    const float* vQ = (const float*)d_in[1];
    const float* WI = (const float*)d_in[2];
    const float* WQ = (const float*)d_in[3];
    const float* bQ = (const float*)d_in[4];
    const float* Wp = (const float*)d_in[5];
    // d_in[6] (b_p): constant added to all logits -> cancels in softmax.

    float* out_p = (float*)d_out;                    // [B][N]
    float* out_u = out_p + (size_t)B_ * N_;          // [B][D]

    char* ws = (char*)d_ws;
    u16*   Wbf   = (u16*)ws;                             // 128 KiB @ 0
    float* qatt  = (float*)(ws + 131072);                // 32 KiB
    float* sums  = (float*)(ws + 163840);                // 1 KiB
    float* u_raw = (float*)(ws + 164864);                // 128 KiB
    float* wbuf  = (float*)(ws + 295936);                // 1 MiB

    k_prep<<<128, 128, 0, stream>>>(WI, vQ, WQ, bQ, Wbf, qatt, sums, u_raw);
    k_fused<<<dim3(N_ / 64, B_), 512, 0, stream>>>(vI, Wbf, qatt, Wp,
                                                   wbuf, sums, u_raw);
    k_fin<<<dim3(B_, 4), 256, 0, stream>>>(wbuf, sums, u_raw, vQ, out_p, out_u);
}